// Round 14
// baseline (284.041 us; speedup 1.0000x reference)
//
#include <hip/hip_runtime.h>
#include <hip/hip_bf16.h>

#define NTOK 512
#define TJ 32
#define EPSF 1e-5f

typedef __attribute__((ext_vector_type(4))) float f32x4;
typedef __attribute__((ext_vector_type(8))) short bf16x8;
typedef __attribute__((ext_vector_type(4))) short bf16x4;

struct HL { short hi; short lo; };

__device__ __forceinline__ short f2bf(float x) {
  __hip_bfloat16 h = __float2bfloat16(x);
  return *reinterpret_cast<short*>(&h);
}
__device__ __forceinline__ float bf2f(short s) {
  unsigned int u = ((unsigned int)(unsigned short)s) << 16;
  return __uint_as_float(u);
}
__device__ __forceinline__ HL splitbf(float x) {
  HL r; r.hi = f2bf(x); r.lo = f2bf(x - bf2f(r.hi)); return r;
}

// ---------------- kernel 1: per (i, j-half) partial messages ----------------
// 1024 blocks (i*2+half), 256 threads, 8 tiles of 32 j.
// LDS 31.5 KB -> 4 blocks/CU (launch_bounds 256,4).
// Phase A: H = silu(RBF*WA^T+ba) via 3xBF16 MFMA; phase B A-frags built in-register.
// Epilogue: contract partial ACC with wb -> 128 floats to ws[(i*2+half)*128].
#define OFF_F0   0
#define OFF_F1   640
#define OFF_RH   2304
#define OFF_MK   2400
#define OFF_BIAS 2432
#define OFF_H    2944
#define SMEM_FLOATS 8064

__global__ __launch_bounds__(256, 4) void tfn_half(
    const float* __restrict__ f0,  const float* __restrict__ f1,
    const float* __restrict__ rbf, const float* __restrict__ rhat,
    const int*  __restrict__ mask,
    const float* __restrict__ w00a, const float* __restrict__ b00a,
    const float* __restrict__ w00b, const float* __restrict__ b00b,
    const float* __restrict__ w10a, const float* __restrict__ b10a,
    const float* __restrict__ w10b, const float* __restrict__ b10b,
    const float* __restrict__ w01a, const float* __restrict__ b01a,
    const float* __restrict__ w01b, const float* __restrict__ b01b,
    const float* __restrict__ w11a, const float* __restrict__ b11a,
    const float* __restrict__ w11b, const float* __restrict__ b11b,
    float* __restrict__ ws)
{
  __shared__ __align__(16) float smem[SMEM_FLOATS];
  short* Hh = (short*)(smem + OFF_H);          // [h][j] stride 40, 5120 shorts
  short* Hl = Hh + 5120;
  float* ACCf = smem + OFF_H;                  // overlay after main loop (4224 floats)
  float* biasb = smem + OFF_BIAS;              // [m][quad] 512 floats

  const int bid = blockIdx.x;
  const int i = bid >> 1;
  const int half = bid & 1;
  const int jbase0 = half * 256;
  const int t = threadIdx.x;
  const int w = t >> 6;
  const int lane = t & 63;
  const int col = lane & 15;
  const int quad = lane >> 4;

  // ---- WA B-fragments (hi/lo) + ba for this wave's two h-tiles ----
  const int hn0 = 2*w, hn1 = 2*w + 1;
  bf16x8 bw0h = {0,0,0,0,0,0,0,0}, bw0l = {0,0,0,0,0,0,0,0};
  bf16x8 bw1h = {0,0,0,0,0,0,0,0}, bw1l = {0,0,0,0,0,0,0,0};
  float ba0v, ba1v;
  {
    const int h0 = hn0*16 + col, h1 = hn1*16 + col;
    const float* r0 = (h0 < 32) ? (w00a + h0*16) : (h0 < 64) ? (w10a + (h0-32)*16)
                    : (h0 < 96) ? (w01a + (h0-64)*16) : (w11a + (h0-96)*16);
    const float* r1 = (h1 < 32) ? (w00a + h1*16) : (h1 < 64) ? (w10a + (h1-32)*16)
                    : (h1 < 96) ? (w01a + (h1-64)*16) : (w11a + (h1-96)*16);
    ba0v = (h0 < 32) ? b00a[h0] : (h0 < 64) ? b10a[h0-32] : (h0 < 96) ? b01a[h0-64] : b11a[h0-96];
    ba1v = (h1 < 32) ? b00a[h1] : (h1 < 64) ? b10a[h1-32] : (h1 < 96) ? b01a[h1-64] : b11a[h1-96];
    if (quad < 2) {
      #pragma unroll
      for (int e = 0; e < 8; ++e) {
        HL s0 = splitbf(r0[quad*8 + e]); bw0h[e] = s0.hi; bw0l[e] = s0.lo;
        HL s1 = splitbf(r1[quad*8 + e]); bw1h[e] = s1.hi; bw1l[e] = s1.lo;
      }
    }
  }

  // ---- prefetch rbf A-frag rows for tile 0 ----
  float4 cr00, cr01, cr10, cr11;
  if (quad < 2) {
    const float* pr = rbf + ((size_t)i*NTOK + jbase0 + col)*16 + quad*8;
    cr00 = *(const float4*)pr;         cr01 = *(const float4*)(pr+4);
    cr10 = *(const float4*)(pr+256);   cr11 = *(const float4*)(pr+260);
  }

  f32x4 acc[4] = {{0.f,0.f,0.f,0.f},{0.f,0.f,0.f,0.f},{0.f,0.f,0.f,0.f},{0.f,0.f,0.f,0.f}};
  float biasp0 = 0.f, biasp1 = 0.f;
  const f32x4 zc = {0.f,0.f,0.f,0.f};

  for (int tile = 0; tile < 8; ++tile) {
    const int j0n = jbase0 + tile*TJ;
    // ---- stage tile inputs (direct) ----
    if (t < 128) *(float4*)&smem[OFF_F0 + (t>>2)*20 + (t&3)*4] =
        *(const float4*)(f0 + (j0n + (t>>2))*16 + (t&3)*4);
    { const int jj = t/12, e = t%12;
      *(float4*)&smem[OFF_F1 + jj*52 + e*4] = *(const float4*)(f1 + (j0n + jj)*48 + e*4); }
    if (t < 128) { const int q2 = t+256, jj = q2/12, e = q2%12;
      *(float4*)&smem[OFF_F1 + jj*52 + e*4] = *(const float4*)(f1 + (j0n + jj)*48 + e*4); }
    if (t < 24) *(float4*)&smem[OFF_RH + t*4] =
        *(const float4*)(rhat + ((size_t)i*NTOK + j0n)*3 + t*4);
    if (t < 8) {
      int4 mv = *(const int4*)(mask + (size_t)i*NTOK + j0n + t*4);
      smem[OFF_MK + t*4+0] = mv.x ? 1.f : 0.f; smem[OFF_MK + t*4+1] = mv.y ? 1.f : 0.f;
      smem[OFF_MK + t*4+2] = mv.z ? 1.f : 0.f; smem[OFF_MK + t*4+3] = mv.w ? 1.f : 0.f;
    }
    __syncthreads();  // B1: staging visible; H free (everyone past prev phase B)

    // ---- phase-A A-frags (hi/lo) from prefetched rbf regs ----
    bf16x8 a0h = {0,0,0,0,0,0,0,0}, a0l = {0,0,0,0,0,0,0,0};
    bf16x8 a1h = {0,0,0,0,0,0,0,0}, a1l = {0,0,0,0,0,0,0,0};
    if (quad < 2) {
      const float v0[8] = {cr00.x,cr00.y,cr00.z,cr00.w,cr01.x,cr01.y,cr01.z,cr01.w};
      const float v1[8] = {cr10.x,cr10.y,cr10.z,cr10.w,cr11.x,cr11.y,cr11.z,cr11.w};
      #pragma unroll
      for (int e = 0; e < 8; ++e) {
        HL s0 = splitbf(v0[e]); a0h[e] = s0.hi; a0l[e] = s0.lo;
        HL s1 = splitbf(v1[e]); a1h[e] = s1.hi; a1l[e] = s1.lo;
      }
    }
    // ---- prefetch rbf for tile+1 ----
    if (tile + 1 < 8 && quad < 2) {
      const float* pr = rbf + ((size_t)i*NTOK + jbase0 + (tile+1)*TJ + col)*16 + quad*8;
      cr00 = *(const float4*)pr;       cr01 = *(const float4*)(pr+4);
      cr10 = *(const float4*)(pr+256); cr11 = *(const float4*)(pr+260);
    }

    // ---- in-register phase-B A-frags (lhs) ----
    // m0 = 32w+col, m1 = 32w+16+col; j = quad*8+e; branch wave-uniform.
    bf16x8 af0h, af0l, af1h, af1l;
    {
      float b0 = 0.f, b1 = 0.f;
      #pragma unroll
      for (int e = 0; e < 8; ++e) {
        const int j = quad*8 + e;
        const float mk = smem[OFF_MK + j];
        float v0, v1;
        if (w == 0) {
          v0 = mk * smem[OFF_F0 + j*20 + col];
          v1 = mk * (smem[OFF_RH+j*3+0]*smem[OFF_F1+j*52+col*3+0]
                   + smem[OFF_RH+j*3+1]*smem[OFF_F1+j*52+col*3+1]
                   + smem[OFF_RH+j*3+2]*smem[OFF_F1+j*52+col*3+2]);
        } else if (w == 1) {
          const int mm0 = col, mm1 = 16+col;
          v0 = mk * smem[OFF_F0 + j*20 + mm0/3] * smem[OFF_RH + j*3 + mm0%3];
          v1 = mk * smem[OFF_F0 + j*20 + mm1/3] * smem[OFF_RH + j*3 + mm1%3];
        } else if (w == 2) {
          const int mm0 = 32+col;
          v0 = mk * smem[OFF_F0 + j*20 + mm0/3] * smem[OFF_RH + j*3 + mm0%3];
          v1 = mk * smem[OFF_F1 + j*52 + col];
        } else {
          v0 = mk * smem[OFF_F1 + j*52 + 16+col];
          v1 = mk * smem[OFF_F1 + j*52 + 32+col];
        }
        HL s0 = splitbf(v0); af0h[e] = s0.hi; af0l[e] = s0.lo;
        HL s1 = splitbf(v1); af1h[e] = s1.hi; af1l[e] = s1.lo;
        b0 += v0; b1 += v1;
      }
      biasp0 += b0; biasp1 += b1;
    }

    // ---- phase A: 3xBF16 MFMA + silu -> Hh/Hl ----
    {
      f32x4 d00 = __builtin_amdgcn_mfma_f32_16x16x32_bf16(a0l, bw0h, zc, 0, 0, 0);
      d00 = __builtin_amdgcn_mfma_f32_16x16x32_bf16(a0h, bw0l, d00, 0, 0, 0);
      d00 = __builtin_amdgcn_mfma_f32_16x16x32_bf16(a0h, bw0h, d00, 0, 0, 0);
      f32x4 d01 = __builtin_amdgcn_mfma_f32_16x16x32_bf16(a0l, bw1h, zc, 0, 0, 0);
      d01 = __builtin_amdgcn_mfma_f32_16x16x32_bf16(a0h, bw1l, d01, 0, 0, 0);
      d01 = __builtin_amdgcn_mfma_f32_16x16x32_bf16(a0h, bw1h, d01, 0, 0, 0);
      f32x4 d10 = __builtin_amdgcn_mfma_f32_16x16x32_bf16(a1l, bw0h, zc, 0, 0, 0);
      d10 = __builtin_amdgcn_mfma_f32_16x16x32_bf16(a1h, bw0l, d10, 0, 0, 0);
      d10 = __builtin_amdgcn_mfma_f32_16x16x32_bf16(a1h, bw0h, d10, 0, 0, 0);
      f32x4 d11 = __builtin_amdgcn_mfma_f32_16x16x32_bf16(a1l, bw1h, zc, 0, 0, 0);
      d11 = __builtin_amdgcn_mfma_f32_16x16x32_bf16(a1h, bw1l, d11, 0, 0, 0);
      d11 = __builtin_amdgcn_mfma_f32_16x16x32_bf16(a1h, bw1h, d11, 0, 0, 0);
      bf16x4 hv, lv;
      #pragma unroll
      for (int r = 0; r < 4; ++r) { float p = d00[r] + ba0v; float s = p/(1.f+__expf(-p)); HL e2 = splitbf(s); hv[r]=e2.hi; lv[r]=e2.lo; }
      *(bf16x4*)&Hh[(hn0*16+col)*40 + 0*16 + quad*4] = hv;
      *(bf16x4*)&Hl[(hn0*16+col)*40 + 0*16 + quad*4] = lv;
      #pragma unroll
      for (int r = 0; r < 4; ++r) { float p = d01[r] + ba1v; float s = p/(1.f+__expf(-p)); HL e2 = splitbf(s); hv[r]=e2.hi; lv[r]=e2.lo; }
      *(bf16x4*)&Hh[(hn1*16+col)*40 + 0*16 + quad*4] = hv;
      *(bf16x4*)&Hl[(hn1*16+col)*40 + 0*16 + quad*4] = lv;
      #pragma unroll
      for (int r = 0; r < 4; ++r) { float p = d10[r] + ba0v; float s = p/(1.f+__expf(-p)); HL e2 = splitbf(s); hv[r]=e2.hi; lv[r]=e2.lo; }
      *(bf16x4*)&Hh[(hn0*16+col)*40 + 1*16 + quad*4] = hv;
      *(bf16x4*)&Hl[(hn0*16+col)*40 + 1*16 + quad*4] = lv;
      #pragma unroll
      for (int r = 0; r < 4; ++r) { float p = d11[r] + ba1v; float s = p/(1.f+__expf(-p)); HL e2 = splitbf(s); hv[r]=e2.hi; lv[r]=e2.lo; }
      *(bf16x4*)&Hh[(hn1*16+col)*40 + 1*16 + quad*4] = hv;
      *(bf16x4*)&Hl[(hn1*16+col)*40 + 1*16 + quad*4] = lv;
    }
    __syncthreads();  // B2: H visible; staging consumed

    // ---- phase B: ACC += LHS^T * H (3xBF16) ----
    #pragma unroll
    for (int k = 0; k < 4; ++k) {
      const int hn = (w==0) ? k : (w==1) ? (4+(k&1)) : (w==2) ? (4+k) : (6+(k&1));
      const bf16x8 bfh = *(const bf16x8*)&Hh[(hn*16+col)*40 + quad*8];
      const bf16x8 bfl = *(const bf16x8*)&Hl[(hn*16+col)*40 + quad*8];
      const bf16x8 ah = (k < 2) ? af0h : af1h;
      const bf16x8 al = (k < 2) ? af0l : af1l;
      acc[k] = __builtin_amdgcn_mfma_f32_16x16x32_bf16(al, bfh, acc[k], 0, 0, 0);
      acc[k] = __builtin_amdgcn_mfma_f32_16x16x32_bf16(ah, bfl, acc[k], 0, 0, 0);
      acc[k] = __builtin_amdgcn_mfma_f32_16x16x32_bf16(ah, bfh, acc[k], 0, 0, 0);
    }
  }

  // ---- dump ACC frags (overlay on H) + bias partials ----
  __syncthreads();
  #pragma unroll
  for (int k = 0; k < 4; ++k) {
    const int mt = 2*w + (k>>1);
    const int hn = (w==0) ? k : (w==1) ? (4+(k&1)) : (w==2) ? (4+k) : (6+(k&1));
    #pragma unroll
    for (int r = 0; r < 4; ++r)
      ACCf[(mt*16 + quad*4 + r)*33 + (hn&1)*16 + col] = acc[k][r];
  }
  biasb[(32*w + col)*4 + quad] = biasp0;
  biasb[(32*w + 16 + col)*4 + quad] = biasp1;
  __syncthreads();

  // ---- contract partial ACC with second-layer weights -> ws ----
  float* wsb = ws + (size_t)bid * 128;
  if (t < 16) {
    const int o = t; float s = 0.f;
    for (int d = 0; d < 16; ++d) {
      const float* wrow = w00b + (d*16 + o)*32;
      float ss = 0.f;
      #pragma unroll
      for (int h = 0; h < 32; ++h) ss += wrow[h] * ACCf[d*33 + h];
      const float bv = biasb[d*4]+biasb[d*4+1]+biasb[d*4+2]+biasb[d*4+3];
      s += ss + b00b[d*16 + o] * bv;
    }
    wsb[o] = s;
  } else if (t < 32) {
    const int o = t - 16; float s = 0.f;
    for (int c = 0; c < 16; ++c) {
      const float* wrow = w10b + (c*16 + o)*32;
      const int m = 16 + c;
      float ss = 0.f;
      #pragma unroll
      for (int h = 0; h < 32; ++h) ss += wrow[h] * ACCf[m*33 + h];
      const float bv = biasb[m*4]+biasb[m*4+1]+biasb[m*4+2]+biasb[m*4+3];
      s += ss + b10b[c*16 + o] * bv;
    }
    wsb[16 + o] = s;
  } else if (t < 80) {
    const int idx = t - 32, g = idx/3, x = idx%3; float s = 0.f;
    for (int f = 0; f < 16; ++f) {
      const float* wrow = w01b + (f*16 + g)*32;
      const int m = 32 + f*3 + x;
      float ss = 0.f;
      #pragma unroll
      for (int h = 0; h < 32; ++h) ss += wrow[h] * ACCf[m*33 + h];
      const float bv = biasb[m*4]+biasb[m*4+1]+biasb[m*4+2]+biasb[m*4+3];
      s += ss + b01b[f*16 + g] * bv;
    }
    wsb[32 + idx] = s;
  } else if (t < 128) {
    const int idx = t - 80, g = idx/3, x = idx%3; float s = 0.f;
    for (int k = 0; k < 16; ++k) {
      const float* wrow = w11b + (k*16 + g)*32;
      const int m = 80 + k*3 + x;
      float ss = 0.f;
      #pragma unroll
      for (int h = 0; h < 32; ++h) ss += wrow[h] * ACCf[m*33 + h];
      const float bv = biasb[m*4]+biasb[m*4+1]+biasb[m*4+2]+biasb[m*4+3];
      s += ss + b11b[k*16 + g] * bv;
    }
    wsb[80 + idx] = s;
  }
}

// ---------------- kernel 2: combine halves + LayerNorms ----------------
__global__ __launch_bounds__(64) void tfn_final(
    const float* __restrict__ ws,
    const float* __restrict__ g0, const float* __restrict__ be0,
    const float* __restrict__ g1, const float* __restrict__ be1,
    float* __restrict__ out)
{
  __shared__ float sm[128];
  __shared__ float rawb[48], nrms[16];
  const int i = blockIdx.x;
  const int t = threadIdx.x;
  sm[t]      = ws[(size_t)i*256 + t]      + ws[(size_t)i*256 + 128 + t];
  sm[t + 64] = ws[(size_t)i*256 + 64 + t] + ws[(size_t)i*256 + 192 + t];
  __syncthreads();
  if (t < 16) {
    float v = sm[t] + sm[16 + t];
    float mu = 0.f;
    #pragma unroll
    for (int k = 0; k < 16; ++k) mu += sm[k] + sm[16 + k];
    mu *= (1.f/16.f);
    float var = 0.f;
    #pragma unroll
    for (int k = 0; k < 16; ++k) { float d = sm[k] + sm[16 + k] - mu; var += d*d; }
    var *= (1.f/16.f);
    out[(size_t)i*16 + t] = (v - mu) * rsqrtf(var + EPSF) * g0[t] + be0[t];
    float r0v = sm[32 + t*3+0] + sm[80 + t*3+0];
    float r1v = sm[32 + t*3+1] + sm[80 + t*3+1];
    float r2v = sm[32 + t*3+2] + sm[80 + t*3+2];
    rawb[t*3+0] = r0v; rawb[t*3+1] = r1v; rawb[t*3+2] = r2v;
    nrms[t] = fmaxf(sqrtf(r0v*r0v + r1v*r1v + r2v*r2v), 1e-8f);
  }
  __syncthreads();
  if (t < 16) {
    float mu = 0.f;
    #pragma unroll
    for (int k = 0; k < 16; ++k) mu += nrms[k];
    mu *= (1.f/16.f);
    float var = 0.f;
    #pragma unroll
    for (int k = 0; k < 16; ++k) { float d = nrms[k] - mu; var += d*d; }
    var *= (1.f/16.f);
    const float ln = (nrms[t] - mu) * rsqrtf(var + EPSF) * g1[t] + be1[t];
    const float scale = ln / nrms[t];
    const size_t base = (size_t)NTOK*16 + (size_t)i*48 + t*3;
    out[base+0] = rawb[t*3+0] * scale;
    out[base+1] = rawb[t*3+1] * scale;
    out[base+2] = rawb[t*3+2] * scale;
  }
}

extern "C" void kernel_launch(void* const* d_in, const int* in_sizes, int n_in,
                              void* d_out, int out_size, void* d_ws, size_t ws_size,
                              hipStream_t stream) {
  int idx_f0 = -1, idx_f1 = -1, idx_rbf = -1, idx_rhat = -1, idx_mask = -1;
  int wa_i[4], ba_i[4], wb_i[4], bb_i[4], g_i[4];
  int nwa = 0, nba = 0, nwb = 0, nbb = 0, ng = 0;
  for (int k = 0; k < n_in; ++k) {
    const int s = in_sizes[k];
    if      (s == 4194304) idx_rbf  = k;
    else if (s == 786432)  idx_rhat = k;
    else if (s == 262144)  idx_mask = k;
    else if (s == 24576)   idx_f1   = k;
    else if (s == 8192)    { if (idx_f0 < 0) idx_f0 = k; else if (nwb < 4) wb_i[nwb++] = k; }
    else if (s == 512)     { if (nwa < 4) wa_i[nwa++] = k; }
    else if (s == 32)      { if (nba < 4) ba_i[nba++] = k; }
    else if (s == 256)     { if (nbb < 4) bb_i[nbb++] = k; }
    else if (s == 16)      { if (ng  < 4) g_i[ng++]  = k; }
  }
  const bool ok = idx_f0 >= 0 && idx_f1 >= 0 && idx_rbf >= 0 && idx_rhat >= 0 &&
                  idx_mask >= 0 && nwa == 4 && nba == 4 && nwb == 4 && nbb == 4 && ng == 4;
  if (!ok) {
    idx_f0 = 1; idx_f1 = 2; idx_rbf = 3; idx_rhat = 4; idx_mask = 5;
    for (int q = 0; q < 4; ++q) {
      wa_i[q] = 6 + q*4; ba_i[q] = 7 + q*4; wb_i[q] = 8 + q*4; bb_i[q] = 9 + q*4;
      g_i[q] = 22 + q;
    }
  }
  float* ws = (float*)d_ws;
  tfn_half<<<1024, 256, 0, stream>>>(
      (const float*)d_in[idx_f0],  (const float*)d_in[idx_f1],
      (const float*)d_in[idx_rbf], (const float*)d_in[idx_rhat],
      (const int*)d_in[idx_mask],
      (const float*)d_in[wa_i[0]], (const float*)d_in[ba_i[0]],
      (const float*)d_in[wb_i[0]], (const float*)d_in[bb_i[0]],
      (const float*)d_in[wa_i[1]], (const float*)d_in[ba_i[1]],
      (const float*)d_in[wb_i[1]], (const float*)d_in[bb_i[1]],
      (const float*)d_in[wa_i[2]], (const float*)d_in[ba_i[2]],
      (const float*)d_in[wb_i[2]], (const float*)d_in[bb_i[2]],
      (const float*)d_in[wa_i[3]], (const float*)d_in[ba_i[3]],
      (const float*)d_in[wb_i[3]], (const float*)d_in[bb_i[3]],
      ws);
  tfn_final<<<512, 64, 0, stream>>>(
      ws,
      (const float*)d_in[g_i[0]], (const float*)d_in[g_i[1]],
      (const float*)d_in[g_i[2]], (const float*)d_in[g_i[3]],
      (float*)d_out);
}

// Round 15
// 215.544 us; speedup vs baseline: 1.3178x; 1.3178x over previous
//
#include <hip/hip_runtime.h>
#include <hip/hip_bf16.h>

#define NTOK 512
#define TJ 32
#define EPSF 1e-5f

typedef __attribute__((ext_vector_type(4))) float f32x4;
typedef __attribute__((ext_vector_type(8))) short bf16x8;
typedef __attribute__((ext_vector_type(4))) short bf16x4;

struct HL { short hi; short lo; };

__device__ __forceinline__ short f2bf(float x) {
  __hip_bfloat16 h = __float2bfloat16(x);
  return *reinterpret_cast<short*>(&h);
}
__device__ __forceinline__ float bf2f(short s) {
  unsigned int u = ((unsigned int)(unsigned short)s) << 16;
  return __uint_as_float(u);
}
__device__ __forceinline__ HL splitbf(float x) {
  HL r; r.hi = f2bf(x); r.lo = f2bf(x - bf2f(r.hi)); return r;
}

// ---------------- kernel 1: per (i, j-half) partial messages ----------------
// 1024 blocks (i*2+half), 256 threads, 8 tiles of 32 j.
// LDS 31.5 KB; launch_bounds(256,2) -> VGPR ~112, no spill (r14 lesson:
// (256,4) clamps to 64 VGPR -> 100 MB scratch spill traffic).
#define OFF_F0   0
#define OFF_F1   640
#define OFF_RH   2304
#define OFF_MK   2400
#define OFF_BIAS 2432
#define OFF_H    2944
#define SMEM_FLOATS 8064

__global__ __launch_bounds__(256, 2) void tfn_half(
    const float* __restrict__ f0,  const float* __restrict__ f1,
    const float* __restrict__ rbf, const float* __restrict__ rhat,
    const int*  __restrict__ mask,
    const float* __restrict__ w00a, const float* __restrict__ b00a,
    const float* __restrict__ w00b, const float* __restrict__ b00b,
    const float* __restrict__ w10a, const float* __restrict__ b10a,
    const float* __restrict__ w10b, const float* __restrict__ b10b,
    const float* __restrict__ w01a, const float* __restrict__ b01a,
    const float* __restrict__ w01b, const float* __restrict__ b01b,
    const float* __restrict__ w11a, const float* __restrict__ b11a,
    const float* __restrict__ w11b, const float* __restrict__ b11b,
    float* __restrict__ ws)
{
  __shared__ __align__(16) float smem[SMEM_FLOATS];
  short* Hh = (short*)(smem + OFF_H);          // [h][j] stride 40, 5120 shorts
  short* Hl = Hh + 5120;
  float* ACCf = smem + OFF_H;                  // overlay after main loop (4224 floats)
  float* biasb = smem + OFF_BIAS;              // [m][quad] 512 floats

  const int bid = blockIdx.x;
  const int i = bid >> 1;
  const int half = bid & 1;
  const int jbase0 = half * 256;
  const int t = threadIdx.x;
  const int w = t >> 6;
  const int lane = t & 63;
  const int col = lane & 15;
  const int quad = lane >> 4;

  // ---- WA B-fragments (hi/lo) + ba for this wave's two h-tiles ----
  const int hn0 = 2*w, hn1 = 2*w + 1;
  bf16x8 bw0h = {0,0,0,0,0,0,0,0}, bw0l = {0,0,0,0,0,0,0,0};
  bf16x8 bw1h = {0,0,0,0,0,0,0,0}, bw1l = {0,0,0,0,0,0,0,0};
  float ba0v, ba1v;
  {
    const int h0 = hn0*16 + col, h1 = hn1*16 + col;
    const float* r0 = (h0 < 32) ? (w00a + h0*16) : (h0 < 64) ? (w10a + (h0-32)*16)
                    : (h0 < 96) ? (w01a + (h0-64)*16) : (w11a + (h0-96)*16);
    const float* r1 = (h1 < 32) ? (w00a + h1*16) : (h1 < 64) ? (w10a + (h1-32)*16)
                    : (h1 < 96) ? (w01a + (h1-64)*16) : (w11a + (h1-96)*16);
    ba0v = (h0 < 32) ? b00a[h0] : (h0 < 64) ? b10a[h0-32] : (h0 < 96) ? b01a[h0-64] : b11a[h0-96];
    ba1v = (h1 < 32) ? b00a[h1] : (h1 < 64) ? b10a[h1-32] : (h1 < 96) ? b01a[h1-64] : b11a[h1-96];
    if (quad < 2) {
      #pragma unroll
      for (int e = 0; e < 8; ++e) {
        HL s0 = splitbf(r0[quad*8 + e]); bw0h[e] = s0.hi; bw0l[e] = s0.lo;
        HL s1 = splitbf(r1[quad*8 + e]); bw1h[e] = s1.hi; bw1l[e] = s1.lo;
      }
    }
  }

  // ---- prefetch rbf A-frag rows for tile 0 ----
  float4 cr00, cr01, cr10, cr11;
  if (quad < 2) {
    const float* pr = rbf + ((size_t)i*NTOK + jbase0 + col)*16 + quad*8;
    cr00 = *(const float4*)pr;         cr01 = *(const float4*)(pr+4);
    cr10 = *(const float4*)(pr+256);   cr11 = *(const float4*)(pr+260);
  }

  f32x4 acc[4] = {{0.f,0.f,0.f,0.f},{0.f,0.f,0.f,0.f},{0.f,0.f,0.f,0.f},{0.f,0.f,0.f,0.f}};
  float biasp0 = 0.f, biasp1 = 0.f;
  const f32x4 zc = {0.f,0.f,0.f,0.f};

  for (int tile = 0; tile < 8; ++tile) {
    const int j0n = jbase0 + tile*TJ;
    // ---- stage tile inputs (direct) ----
    if (t < 128) *(float4*)&smem[OFF_F0 + (t>>2)*20 + (t&3)*4] =
        *(const float4*)(f0 + (j0n + (t>>2))*16 + (t&3)*4);
    { const int jj = t/12, e = t%12;
      *(float4*)&smem[OFF_F1 + jj*52 + e*4] = *(const float4*)(f1 + (j0n + jj)*48 + e*4); }
    if (t < 128) { const int q2 = t+256, jj = q2/12, e = q2%12;
      *(float4*)&smem[OFF_F1 + jj*52 + e*4] = *(const float4*)(f1 + (j0n + jj)*48 + e*4); }
    if (t < 24) *(float4*)&smem[OFF_RH + t*4] =
        *(const float4*)(rhat + ((size_t)i*NTOK + j0n)*3 + t*4);
    if (t < 8) {
      int4 mv = *(const int4*)(mask + (size_t)i*NTOK + j0n + t*4);
      smem[OFF_MK + t*4+0] = mv.x ? 1.f : 0.f; smem[OFF_MK + t*4+1] = mv.y ? 1.f : 0.f;
      smem[OFF_MK + t*4+2] = mv.z ? 1.f : 0.f; smem[OFF_MK + t*4+3] = mv.w ? 1.f : 0.f;
    }
    __syncthreads();  // B1: staging visible; H free (everyone past prev phase B)

    // ---- phase-A A-frags (hi/lo) from prefetched rbf regs ----
    bf16x8 a0h = {0,0,0,0,0,0,0,0}, a0l = {0,0,0,0,0,0,0,0};
    bf16x8 a1h = {0,0,0,0,0,0,0,0}, a1l = {0,0,0,0,0,0,0,0};
    if (quad < 2) {
      const float v0[8] = {cr00.x,cr00.y,cr00.z,cr00.w,cr01.x,cr01.y,cr01.z,cr01.w};
      const float v1[8] = {cr10.x,cr10.y,cr10.z,cr10.w,cr11.x,cr11.y,cr11.z,cr11.w};
      #pragma unroll
      for (int e = 0; e < 8; ++e) {
        HL s0 = splitbf(v0[e]); a0h[e] = s0.hi; a0l[e] = s0.lo;
        HL s1 = splitbf(v1[e]); a1h[e] = s1.hi; a1l[e] = s1.lo;
      }
    }
    // ---- prefetch rbf for tile+1 ----
    if (tile + 1 < 8 && quad < 2) {
      const float* pr = rbf + ((size_t)i*NTOK + jbase0 + (tile+1)*TJ + col)*16 + quad*8;
      cr00 = *(const float4*)pr;       cr01 = *(const float4*)(pr+4);
      cr10 = *(const float4*)(pr+256); cr11 = *(const float4*)(pr+260);
    }

    // ---- in-register phase-B A-frags (lhs) ----
    // m0 = 32w+col, m1 = 32w+16+col; j = quad*8+e; branch wave-uniform.
    bf16x8 af0h, af0l, af1h, af1l;
    {
      float b0 = 0.f, b1 = 0.f;
      #pragma unroll
      for (int e = 0; e < 8; ++e) {
        const int j = quad*8 + e;
        const float mk = smem[OFF_MK + j];
        float v0, v1;
        if (w == 0) {
          v0 = mk * smem[OFF_F0 + j*20 + col];
          v1 = mk * (smem[OFF_RH+j*3+0]*smem[OFF_F1+j*52+col*3+0]
                   + smem[OFF_RH+j*3+1]*smem[OFF_F1+j*52+col*3+1]
                   + smem[OFF_RH+j*3+2]*smem[OFF_F1+j*52+col*3+2]);
        } else if (w == 1) {
          const int mm0 = col, mm1 = 16+col;
          v0 = mk * smem[OFF_F0 + j*20 + mm0/3] * smem[OFF_RH + j*3 + mm0%3];
          v1 = mk * smem[OFF_F0 + j*20 + mm1/3] * smem[OFF_RH + j*3 + mm1%3];
        } else if (w == 2) {
          const int mm0 = 32+col;
          v0 = mk * smem[OFF_F0 + j*20 + mm0/3] * smem[OFF_RH + j*3 + mm0%3];
          v1 = mk * smem[OFF_F1 + j*52 + col];
        } else {
          v0 = mk * smem[OFF_F1 + j*52 + 16+col];
          v1 = mk * smem[OFF_F1 + j*52 + 32+col];
        }
        HL s0 = splitbf(v0); af0h[e] = s0.hi; af0l[e] = s0.lo;
        HL s1 = splitbf(v1); af1h[e] = s1.hi; af1l[e] = s1.lo;
        b0 += v0; b1 += v1;
      }
      biasp0 += b0; biasp1 += b1;
    }

    // ---- phase A: 3xBF16 MFMA + silu -> Hh/Hl ----
    {
      f32x4 d00 = __builtin_amdgcn_mfma_f32_16x16x32_bf16(a0l, bw0h, zc, 0, 0, 0);
      d00 = __builtin_amdgcn_mfma_f32_16x16x32_bf16(a0h, bw0l, d00, 0, 0, 0);
      d00 = __builtin_amdgcn_mfma_f32_16x16x32_bf16(a0h, bw0h, d00, 0, 0, 0);
      f32x4 d01 = __builtin_amdgcn_mfma_f32_16x16x32_bf16(a0l, bw1h, zc, 0, 0, 0);
      d01 = __builtin_amdgcn_mfma_f32_16x16x32_bf16(a0h, bw1l, d01, 0, 0, 0);
      d01 = __builtin_amdgcn_mfma_f32_16x16x32_bf16(a0h, bw1h, d01, 0, 0, 0);
      f32x4 d10 = __builtin_amdgcn_mfma_f32_16x16x32_bf16(a1l, bw0h, zc, 0, 0, 0);
      d10 = __builtin_amdgcn_mfma_f32_16x16x32_bf16(a1h, bw0l, d10, 0, 0, 0);
      d10 = __builtin_amdgcn_mfma_f32_16x16x32_bf16(a1h, bw0h, d10, 0, 0, 0);
      f32x4 d11 = __builtin_amdgcn_mfma_f32_16x16x32_bf16(a1l, bw1h, zc, 0, 0, 0);
      d11 = __builtin_amdgcn_mfma_f32_16x16x32_bf16(a1h, bw1l, d11, 0, 0, 0);
      d11 = __builtin_amdgcn_mfma_f32_16x16x32_bf16(a1h, bw1h, d11, 0, 0, 0);
      bf16x4 hv, lv;
      #pragma unroll
      for (int r = 0; r < 4; ++r) { float p = d00[r] + ba0v; float s = p/(1.f+__expf(-p)); HL e2 = splitbf(s); hv[r]=e2.hi; lv[r]=e2.lo; }
      *(bf16x4*)&Hh[(hn0*16+col)*40 + 0*16 + quad*4] = hv;
      *(bf16x4*)&Hl[(hn0*16+col)*40 + 0*16 + quad*4] = lv;
      #pragma unroll
      for (int r = 0; r < 4; ++r) { float p = d01[r] + ba1v; float s = p/(1.f+__expf(-p)); HL e2 = splitbf(s); hv[r]=e2.hi; lv[r]=e2.lo; }
      *(bf16x4*)&Hh[(hn1*16+col)*40 + 0*16 + quad*4] = hv;
      *(bf16x4*)&Hl[(hn1*16+col)*40 + 0*16 + quad*4] = lv;
      #pragma unroll
      for (int r = 0; r < 4; ++r) { float p = d10[r] + ba0v; float s = p/(1.f+__expf(-p)); HL e2 = splitbf(s); hv[r]=e2.hi; lv[r]=e2.lo; }
      *(bf16x4*)&Hh[(hn0*16+col)*40 + 1*16 + quad*4] = hv;
      *(bf16x4*)&Hl[(hn0*16+col)*40 + 1*16 + quad*4] = lv;
      #pragma unroll
      for (int r = 0; r < 4; ++r) { float p = d11[r] + ba1v; float s = p/(1.f+__expf(-p)); HL e2 = splitbf(s); hv[r]=e2.hi; lv[r]=e2.lo; }
      *(bf16x4*)&Hh[(hn1*16+col)*40 + 1*16 + quad*4] = hv;
      *(bf16x4*)&Hl[(hn1*16+col)*40 + 1*16 + quad*4] = lv;
    }
    __syncthreads();  // B2: H visible; staging consumed

    // ---- phase B: ACC += LHS^T * H (3xBF16) ----
    #pragma unroll
    for (int k = 0; k < 4; ++k) {
      const int hn = (w==0) ? k : (w==1) ? (4+(k&1)) : (w==2) ? (4+k) : (6+(k&1));
      const bf16x8 bfh = *(const bf16x8*)&Hh[(hn*16+col)*40 + quad*8];
      const bf16x8 bfl = *(const bf16x8*)&Hl[(hn*16+col)*40 + quad*8];
      const bf16x8 ah = (k < 2) ? af0h : af1h;
      const bf16x8 al = (k < 2) ? af0l : af1l;
      acc[k] = __builtin_amdgcn_mfma_f32_16x16x32_bf16(al, bfh, acc[k], 0, 0, 0);
      acc[k] = __builtin_amdgcn_mfma_f32_16x16x32_bf16(ah, bfl, acc[k], 0, 0, 0);
      acc[k] = __builtin_amdgcn_mfma_f32_16x16x32_bf16(ah, bfh, acc[k], 0, 0, 0);
    }
  }

  // ---- dump ACC frags (overlay on H) + bias partials ----
  __syncthreads();
  #pragma unroll
  for (int k = 0; k < 4; ++k) {
    const int mt = 2*w + (k>>1);
    const int hn = (w==0) ? k : (w==1) ? (4+(k&1)) : (w==2) ? (4+k) : (6+(k&1));
    #pragma unroll
    for (int r = 0; r < 4; ++r)
      ACCf[(mt*16 + quad*4 + r)*33 + (hn&1)*16 + col] = acc[k][r];
  }
  biasb[(32*w + col)*4 + quad] = biasp0;
  biasb[(32*w + 16 + col)*4 + quad] = biasp1;
  __syncthreads();

  // ---- contract partial ACC with second-layer weights -> ws ----
  float* wsb = ws + (size_t)bid * 128;
  if (t < 16) {
    const int o = t; float s = 0.f;
    for (int d = 0; d < 16; ++d) {
      const float* wrow = w00b + (d*16 + o)*32;
      float ss = 0.f;
      #pragma unroll
      for (int h = 0; h < 32; ++h) ss += wrow[h] * ACCf[d*33 + h];
      const float bv = biasb[d*4]+biasb[d*4+1]+biasb[d*4+2]+biasb[d*4+3];
      s += ss + b00b[d*16 + o] * bv;
    }
    wsb[o] = s;
  } else if (t < 32) {
    const int o = t - 16; float s = 0.f;
    for (int c = 0; c < 16; ++c) {
      const float* wrow = w10b + (c*16 + o)*32;
      const int m = 16 + c;
      float ss = 0.f;
      #pragma unroll
      for (int h = 0; h < 32; ++h) ss += wrow[h] * ACCf[m*33 + h];
      const float bv = biasb[m*4]+biasb[m*4+1]+biasb[m*4+2]+biasb[m*4+3];
      s += ss + b10b[c*16 + o] * bv;
    }
    wsb[16 + o] = s;
  } else if (t < 80) {
    const int idx = t - 32, g = idx/3, x = idx%3; float s = 0.f;
    for (int f = 0; f < 16; ++f) {
      const float* wrow = w01b + (f*16 + g)*32;
      const int m = 32 + f*3 + x;
      float ss = 0.f;
      #pragma unroll
      for (int h = 0; h < 32; ++h) ss += wrow[h] * ACCf[m*33 + h];
      const float bv = biasb[m*4]+biasb[m*4+1]+biasb[m*4+2]+biasb[m*4+3];
      s += ss + b01b[f*16 + g] * bv;
    }
    wsb[32 + idx] = s;
  } else if (t < 128) {
    const int idx = t - 80, g = idx/3, x = idx%3; float s = 0.f;
    for (int k = 0; k < 16; ++k) {
      const float* wrow = w11b + (k*16 + g)*32;
      const int m = 80 + k*3 + x;
      float ss = 0.f;
      #pragma unroll
      for (int h = 0; h < 32; ++h) ss += wrow[h] * ACCf[m*33 + h];
      const float bv = biasb[m*4]+biasb[m*4+1]+biasb[m*4+2]+biasb[m*4+3];
      s += ss + b11b[k*16 + g] * bv;
    }
    wsb[80 + idx] = s;
  }
}

// ---------------- kernel 2: combine halves + LayerNorms ----------------
__global__ __launch_bounds__(64) void tfn_final(
    const float* __restrict__ ws,
    const float* __restrict__ g0, const float* __restrict__ be0,
    const float* __restrict__ g1, const float* __restrict__ be1,
    float* __restrict__ out)
{
  __shared__ float sm[128];
  __shared__ float rawb[48], nrms[16];
  const int i = blockIdx.x;
  const int t = threadIdx.x;
  sm[t]      = ws[(size_t)i*256 + t]      + ws[(size_t)i*256 + 128 + t];
  sm[t + 64] = ws[(size_t)i*256 + 64 + t] + ws[(size_t)i*256 + 192 + t];
  __syncthreads();
  if (t < 16) {
    float v = sm[t] + sm[16 + t];
    float mu = 0.f;
    #pragma unroll
    for (int k = 0; k < 16; ++k) mu += sm[k] + sm[16 + k];
    mu *= (1.f/16.f);
    float var = 0.f;
    #pragma unroll
    for (int k = 0; k < 16; ++k) { float d = sm[k] + sm[16 + k] - mu; var += d*d; }
    var *= (1.f/16.f);
    out[(size_t)i*16 + t] = (v - mu) * rsqrtf(var + EPSF) * g0[t] + be0[t];
    float r0v = sm[32 + t*3+0] + sm[80 + t*3+0];
    float r1v = sm[32 + t*3+1] + sm[80 + t*3+1];
    float r2v = sm[32 + t*3+2] + sm[80 + t*3+2];
    rawb[t*3+0] = r0v; rawb[t*3+1] = r1v; rawb[t*3+2] = r2v;
    nrms[t] = fmaxf(sqrtf(r0v*r0v + r1v*r1v + r2v*r2v), 1e-8f);
  }
  __syncthreads();
  if (t < 16) {
    float mu = 0.f;
    #pragma unroll
    for (int k = 0; k < 16; ++k) mu += nrms[k];
    mu *= (1.f/16.f);
    float var = 0.f;
    #pragma unroll
    for (int k = 0; k < 16; ++k) { float d = nrms[k] - mu; var += d*d; }
    var *= (1.f/16.f);
    const float ln = (nrms[t] - mu) * rsqrtf(var + EPSF) * g1[t] + be1[t];
    const float scale = ln / nrms[t];
    const size_t base = (size_t)NTOK*16 + (size_t)i*48 + t*3;
    out[base+0] = rawb[t*3+0] * scale;
    out[base+1] = rawb[t*3+1] * scale;
    out[base+2] = rawb[t*3+2] * scale;
  }
}

extern "C" void kernel_launch(void* const* d_in, const int* in_sizes, int n_in,
                              void* d_out, int out_size, void* d_ws, size_t ws_size,
                              hipStream_t stream) {
  int idx_f0 = -1, idx_f1 = -1, idx_rbf = -1, idx_rhat = -1, idx_mask = -1;
  int wa_i[4], ba_i[4], wb_i[4], bb_i[4], g_i[4];
  int nwa = 0, nba = 0, nwb = 0, nbb = 0, ng = 0;
  for (int k = 0; k < n_in; ++k) {
    const int s = in_sizes[k];
    if      (s == 4194304) idx_rbf  = k;
    else if (s == 786432)  idx_rhat = k;
    else if (s == 262144)  idx_mask = k;
    else if (s == 24576)   idx_f1   = k;
    else if (s == 8192)    { if (idx_f0 < 0) idx_f0 = k; else if (nwb < 4) wb_i[nwb++] = k; }
    else if (s == 512)     { if (nwa < 4) wa_i[nwa++] = k; }
    else if (s == 32)      { if (nba < 4) ba_i[nba++] = k; }
    else if (s == 256)     { if (nbb < 4) bb_i[nbb++] = k; }
    else if (s == 16)      { if (ng  < 4) g_i[ng++]  = k; }
  }
  const bool ok = idx_f0 >= 0 && idx_f1 >= 0 && idx_rbf >= 0 && idx_rhat >= 0 &&
                  idx_mask >= 0 && nwa == 4 && nba == 4 && nwb == 4 && nbb == 4 && ng == 4;
  if (!ok) {
    idx_f0 = 1; idx_f1 = 2; idx_rbf = 3; idx_rhat = 4; idx_mask = 5;
    for (int q = 0; q < 4; ++q) {
      wa_i[q] = 6 + q*4; ba_i[q] = 7 + q*4; wb_i[q] = 8 + q*4; bb_i[q] = 9 + q*4;
      g_i[q] = 22 + q;
    }
  }
  float* ws = (float*)d_ws;
  tfn_half<<<1024, 256, 0, stream>>>(
      (const float*)d_in[idx_f0],  (const float*)d_in[idx_f1],
      (const float*)d_in[idx_rbf], (const float*)d_in[idx_rhat],
      (const int*)d_in[idx_mask],
      (const float*)d_in[wa_i[0]], (const float*)d_in[ba_i[0]],
      (const float*)d_in[wb_i[0]], (const float*)d_in[bb_i[0]],
      (const float*)d_in[wa_i[1]], (const float*)d_in[ba_i[1]],
      (const float*)d_in[wb_i[1]], (const float*)d_in[bb_i[1]],
      (const float*)d_in[wa_i[2]], (const float*)d_in[ba_i[2]],
      (const float*)d_in[wb_i[2]], (const float*)d_in[bb_i[2]],
      (const float*)d_in[wa_i[3]], (const float*)d_in[ba_i[3]],
      (const float*)d_in[wb_i[3]], (const float*)d_in[bb_i[3]],
      ws);
  tfn_final<<<512, 64, 0, stream>>>(
      ws,
      (const float*)d_in[g_i[0]], (const float*)d_in[g_i[1]],
      (const float*)d_in[g_i[2]], (const float*)d_in[g_i[3]],
      (float*)d_out);
}